// Round 3
// baseline (163.259 us; speedup 1.0000x reference)
//
#include <hip/hip_runtime.h>
#include <hip/hip_bf16.h>
#include <math.h>

// GeomAttention: B=2, L=S=2048, H=8, E=D=32, fp32 in/out.
// scores = (0.5*dot - 0.5*relu(qn2*kn2 - dot^2))/sqrt(E); softmax over S; out = attn@V.
// Round 10: barrier-free main kernel. R2 post-mortem showed the per-tile
// __syncthreads (vmcnt(0) drain for global_load_lds) convoyed all waves: 1710
// cyc/block-tile vs ~400 of work. ga_reg loads K/V/kn2 fragments global->register
// per wave (no LDS, no barriers, no DMA), waves fully self-paced; XCD swizzle keeps
// each (bh,strip) group's ~1.8MB working set in one XCD L2. Pre-images unswizzled
// (registers don't bank-conflict). Defer-max + permlane P^T + lacc retained.

#define NB 2
#define NL 2048
#define NS 2048
#define NH 8
#define NBH 16
#define STRIPS 2
#define NT 16                 // 64-key tiles per strip
#define CSC 0.12751742f       // 0.5 / sqrt(32) * log2(e)
#define DEFER_THR 24.0f       // p <= 2^(24*CSC) ~= 8.4, safe in bf16

#define WS_KN2_OFF 0u
#define WS_KHKL_OFF 131072u                          // 16*2048 f32
#define WS_VT_OFF (131072u + 4194304u)               // + 16*2048*128B (K hi/lo image)
#define WS_PACC_OFF (131072u + 4194304u + 2097152u)  // + 16*32*2048*2B (V^T image)
#define WS_PML_OFF (WS_PACC_OFF + 8388608u)          // + 16*2*2048*32 f32
#define WS_NEED (WS_PML_OFF + 524288u)               // + 16*2*2048*2 f32 = 15,335,424 B

typedef float f32x4 __attribute__((ext_vector_type(4)));
typedef float f32x2 __attribute__((ext_vector_type(2)));
typedef short s16x8 __attribute__((ext_vector_type(8)));
typedef unsigned short u16;

__device__ inline unsigned pk2(float a, float b) {  // bf16(a)|bf16(b)<<16, RNE
    __hip_bfloat162 t = __float22bfloat162_rn(make_float2(a, b));
    union { __hip_bfloat162 h; unsigned u; } cv;
    cv.h = t;
    return cv.u;
}
template <int CTRL>
__device__ inline float dpp_add(float x) {
    return x + __int_as_float(__builtin_amdgcn_mov_dpp(__float_as_int(x), CTRL, 0xF, 0xF, false));
}
// gfx950 cross-lane row swaps (both operands read-write)
__device__ inline void pl32(unsigned& a, unsigned& b) {
    asm("v_permlane32_swap_b32 %0, %1" : "+v"(a), "+v"(b));
}
__device__ inline void pl16(unsigned& a, unsigned& b) {
    asm("v_permlane16_swap_b32 %0, %1" : "+v"(a), "+v"(b));
}
// fallback-kernel swizzles
__device__ inline int swzK(int row) { return (row ^ (row >> 2)) & 3; }
__device__ inline int swzV(int row) { return (row + (row >> 3)) & 7; }

// ==== pre-kernel: register-fragment image layouts (no LDS swizzles) ====
// K image: [bh][key] row of 64 u16 = [hi chunks 0..3 | lo chunks 4..7], chunk c =
// bf16 of elements [8c..8c+8). V image: [bh][d][s] linear bf16. kn2 exact fp32.
__global__ __launch_bounds__(256) void ga_pre(const float* __restrict__ K,
                                              const float* __restrict__ V,
                                              float* __restrict__ kn2w,
                                              u16* __restrict__ khkl,
                                              u16* __restrict__ vtw) {
    __shared__ float Vf[64][36];
    const int T = threadIdx.x;
    const int bh = blockIdx.x >> 5, stile = blockIdx.x & 31;
    const int b = bh >> 3, h = bh & 7;
    const int s0 = stile * 64;
    const int sk = T >> 2, kc = T & 3;

    const float* kp = K + ((size_t)((b * NS + s0 + sk) * NH + h)) * 32 + kc * 8;
    float4 f0 = *(const float4*)kp, f1 = *(const float4*)(kp + 4);
    float kx[8] = {f0.x, f0.y, f0.z, f0.w, f1.x, f1.y, f1.z, f1.w};
    unsigned hh[4], ll[4];
    float kn2p = 0.f;
#pragma unroll
    for (int i = 0; i < 4; i++) {
        float x0 = kx[2 * i], x1 = kx[2 * i + 1];
        kn2p = fmaf(x0, x0, kn2p);
        kn2p = fmaf(x1, x1, kn2p);
        unsigned h01 = pk2(x0, x1);
        hh[i] = h01;
        float h0 = __uint_as_float(h01 << 16);
        float h1 = __uint_as_float(h01 & 0xffff0000u);
        ll[i] = pk2(x0 - h0, x1 - h1);
    }
    u16* kd = khkl + ((size_t)(bh * NS + s0 + sk)) * 64;
    *(uint4*)(kd + kc * 8) = make_uint4(hh[0], hh[1], hh[2], hh[3]);
    *(uint4*)(kd + (4 + kc) * 8) = make_uint4(ll[0], ll[1], ll[2], ll[3]);
    kn2p = dpp_add<0xB1>(kn2p);
    kn2p = dpp_add<0x4E>(kn2p);
    if (kc == 0) kn2w[bh * NS + s0 + sk] = kn2p;

    const float* vp = V + ((size_t)((b * NS + s0 + sk) * NH + h)) * 32 + kc * 8;
    float4 g0 = *(const float4*)vp, g1 = *(const float4*)(vp + 4);
    // chunk swizzle keyed on (row>>3)&3 so the column-wise read below is <=2-way banked
    const int chv = kc ^ ((sk >> 3) & 3);
    *(float4*)&Vf[sk][chv * 8] = g0;
    *(float4*)&Vf[sk][chv * 8 + 4] = g1;
    __syncthreads();
    const int dr = T >> 3, c = T & 7;
    float vv[8];
#pragma unroll
    for (int i = 0; i < 8; i++)
        vv[i] = Vf[c * 8 + i][(((dr >> 3) ^ (c & 3)) << 3) + (dr & 7)];
    *(uint4*)(vtw + ((size_t)(bh * 32 + dr)) * NS + s0 + c * 8) =
        make_uint4(pk2(vv[0], vv[1]), pk2(vv[2], vv[3]), pk2(vv[4], vv[5]), pk2(vv[6], vv[7]));
}

// ==== main kernel: barrier-free, LDS-free, per-wave register fragments ====
__global__ __launch_bounds__(256, 3) void ga_reg(
    const float* __restrict__ Q, const float* __restrict__ kn2w,
    const u16* __restrict__ khkl, const u16* __restrict__ vtw,
    float* __restrict__ pacc, float* __restrict__ pml) {
    const int T = threadIdx.x;
    const int lane = T & 63, wave = T >> 6;
    const int g = lane >> 4, lc = lane & 15, g8 = g * 8;
    // XCD swizzle: grp = blk&31 -> (bh,strip); all 32 qt-blocks of a group share
    // blk%8 -> same XCD; 4 groups/XCD, ~1.8MB working set each (fits 4MB L2).
    const int blk = blockIdx.x;
    const int grp = blk & 31, qt = blk >> 5;
    const int bh = grp >> 1, strip = grp & 1;
    const int b = bh >> 3, h = bh & 7;
    const int qw = qt * 64 + wave * 16;
    const int kb0 = strip * 1024;

    // ---- Q fragments (hi/lo bf16) + exact qn2, in-lane ----
    const float* qrow = Q + ((size_t)((b * NL + qw + lc) * NH + h)) * 32 + g8;
    float4 qa = *(const float4*)qrow, qb = *(const float4*)(qrow + 4);
    float q8[8] = {qa.x, qa.y, qa.z, qa.w, qb.x, qb.y, qb.z, qb.w};
    union { unsigned u4[4]; s16x8 v; } qh_, ql_;
    float qn2 = 0.f;
#pragma unroll
    for (int i = 0; i < 4; i++) {
        float x0 = q8[2 * i], x1 = q8[2 * i + 1];
        qn2 = fmaf(x0, x0, qn2);
        qn2 = fmaf(x1, x1, qn2);
        unsigned h01 = pk2(x0, x1);
        qh_.u4[i] = h01;
        float h0 = __uint_as_float(h01 << 16);
        float h1 = __uint_as_float(h01 & 0xffff0000u);
        ql_.u4[i] = pk2(x0 - h0, x1 - h1);
    }
    const s16x8 qh = qh_.v, ql = ql_.v;
    qn2 += __shfl_xor(qn2, 16);
    qn2 += __shfl_xor(qn2, 32);

    // ---- per-lane fragment base pointers (u16 units; rows 128B) ----
    const u16* kbase = khkl + ((size_t)(bh * NS + kb0) + lc) * 64 + g8;
    const u16* vbase = vtw + ((size_t)(bh * 32 + lc)) * NS + kb0 + g8;
    const float* kn2b = kn2w + (size_t)bh * NS + kb0 + 4 * g;

    s16x8 ones;
#pragma unroll
    for (int i = 0; i < 8; i++) ones[i] = (short)0x3F80;  // bf16 1.0

    f32x4 acc0 = {0.f, 0.f, 0.f, 0.f}, acc1 = {0.f, 0.f, 0.f, 0.f};
    f32x4 lacc = {0.f, 0.f, 0.f, 0.f};
    float m = -1e30f;
    const f32x4 z = {0.f, 0.f, 0.f, 0.f};

    for (int t = 0; t < NT; ++t) {
        // ---- issue ALL loads for this tile up front (12 VMEM + 4 broadcast) ----
        const u16* kt = kbase + t * (64 * 64);
        const u16* vt = vbase + t * 64;
        const float* knt = kn2b + t * 64;
        s16x8 kh0 = *(const s16x8*)(kt);              // keys 16*0+lc, k 8g..
        s16x8 kl0 = *(const s16x8*)(kt + 32);
        s16x8 kh1 = *(const s16x8*)(kt + 16 * 64);
        s16x8 kl1 = *(const s16x8*)(kt + 16 * 64 + 32);
        s16x8 kh2 = *(const s16x8*)(kt + 32 * 64);
        s16x8 kl2 = *(const s16x8*)(kt + 32 * 64 + 32);
        s16x8 kh3 = *(const s16x8*)(kt + 48 * 64);
        s16x8 kl3 = *(const s16x8*)(kt + 48 * 64 + 32);
        s16x8 va0 = *(const s16x8*)(vt);              // d=lc,    keys 8g..
        s16x8 va1 = *(const s16x8*)(vt + 32);         // d=lc,    keys 32+8g..
        s16x8 va2 = *(const s16x8*)(vt + 16 * NS);    // d=lc+16, keys 8g..
        s16x8 va3 = *(const s16x8*)(vt + 16 * NS + 32);
        f32x4 kn2v0 = *(const f32x4*)(knt);
        f32x4 kn2v1 = *(const f32x4*)(knt + 16);
        f32x4 kn2v2 = *(const f32x4*)(knt + 32);
        f32x4 kn2v3 = *(const f32x4*)(knt + 48);

        // ---- QK^T (hi*hi + hi*lo + lo*hi) ----
        f32x4 d[4];
        {
            f32x4 dd = __builtin_amdgcn_mfma_f32_16x16x32_bf16(kl0, qh, z, 0, 0, 0);
            dd = __builtin_amdgcn_mfma_f32_16x16x32_bf16(kh0, ql, dd, 0, 0, 0);
            d[0] = __builtin_amdgcn_mfma_f32_16x16x32_bf16(kh0, qh, dd, 0, 0, 0);
            dd = __builtin_amdgcn_mfma_f32_16x16x32_bf16(kl1, qh, z, 0, 0, 0);
            dd = __builtin_amdgcn_mfma_f32_16x16x32_bf16(kh1, ql, dd, 0, 0, 0);
            d[1] = __builtin_amdgcn_mfma_f32_16x16x32_bf16(kh1, qh, dd, 0, 0, 0);
            dd = __builtin_amdgcn_mfma_f32_16x16x32_bf16(kl2, qh, z, 0, 0, 0);
            dd = __builtin_amdgcn_mfma_f32_16x16x32_bf16(kh2, ql, dd, 0, 0, 0);
            d[2] = __builtin_amdgcn_mfma_f32_16x16x32_bf16(kh2, qh, dd, 0, 0, 0);
            dd = __builtin_amdgcn_mfma_f32_16x16x32_bf16(kl3, qh, z, 0, 0, 0);
            dd = __builtin_amdgcn_mfma_f32_16x16x32_bf16(kh3, ql, dd, 0, 0, 0);
            d[3] = __builtin_amdgcn_mfma_f32_16x16x32_bf16(kh3, qh, dd, 0, 0, 0);
        }

        // ---- scores: sc = min(d, d + (d^2 - qn2*kn2)) (pre-CSC log2 domain) ----
        const f32x2 qn2v = {qn2, qn2};
        f32x4 kn2m[4] = {kn2v0, kn2v1, kn2v2, kn2v3};
        float sc[4][4];
#pragma unroll
        for (int st = 0; st < 4; st++) {
            f32x2 dd0 = {d[st][0], d[st][1]}, dd1 = {d[st][2], d[st][3]};
            f32x2 kk0 = {kn2m[st][0], kn2m[st][1]}, kk1 = {kn2m[st][2], kn2m[st][3]};
            f32x2 e0 = dd0 - qn2v * kk0;
            f32x2 e1 = dd1 - qn2v * kk1;
            f32x2 t0 = dd0 * dd0 + e0;
            f32x2 t1 = dd1 * dd1 + e1;
            sc[st][0] = fminf(d[st][0], t0[0]);
            sc[st][1] = fminf(d[st][1], t0[1]);
            sc[st][2] = fminf(d[st][2], t1[0]);
            sc[st][3] = fminf(d[st][3], t1[1]);
        }

        // ---- online softmax with deferred max ----
        float a0 = fmaxf(fmaxf(sc[0][0], sc[0][1]), sc[0][2]);
        float a1 = fmaxf(fmaxf(sc[0][3], sc[1][0]), sc[1][1]);
        float a2 = fmaxf(fmaxf(sc[1][2], sc[1][3]), sc[2][0]);
        float a3 = fmaxf(fmaxf(sc[2][1], sc[2][2]), sc[2][3]);
        float a4 = fmaxf(fmaxf(sc[3][0], sc[3][1]), sc[3][2]);
        float tm = fmaxf(fmaxf(fmaxf(a0, a1), fmaxf(a2, a3)), fmaxf(a4, sc[3][3]));
        if (!__all(tm <= m + DEFER_THR)) {
            tm = fmaxf(tm, __shfl_xor(tm, 16));
            tm = fmaxf(tm, __shfl_xor(tm, 32));
            const float nm = fmaxf(m, tm);
            const float al = __builtin_amdgcn_exp2f((m - nm) * CSC);
            m = nm;
            acc0 *= al;
            acc1 *= al;
            lacc *= al;
        }
        const float negmC = -m * CSC;
        const f32x2 cscv = {CSC, CSC}, nmv = {negmC, negmC};
        float p[4][4];
#pragma unroll
        for (int st = 0; st < 4; st++) {
            f32x2 s0 = {sc[st][0], sc[st][1]}, s1 = {sc[st][2], sc[st][3]};
            f32x2 e0 = s0 * cscv + nmv;
            f32x2 e1 = s1 * cscv + nmv;
            p[st][0] = __builtin_amdgcn_exp2f(e0[0]);
            p[st][1] = __builtin_amdgcn_exp2f(e0[1]);
            p[st][2] = __builtin_amdgcn_exp2f(e1[0]);
            p[st][3] = __builtin_amdgcn_exp2f(e1[1]);
        }

        // ---- P^T in registers: pk2 pack + permlane32/16 swap ----
        unsigned w00 = pk2(p[0][0], p[0][1]), w01 = pk2(p[0][2], p[0][3]);
        unsigned w10 = pk2(p[1][0], p[1][1]), w11 = pk2(p[1][2], p[1][3]);
        unsigned w20 = pk2(p[2][0], p[2][1]), w21 = pk2(p[2][2], p[2][3]);
        unsigned w30 = pk2(p[3][0], p[3][1]), w31 = pk2(p[3][2], p[3][3]);
        pl32(w00, w10); pl32(w01, w11);
        pl16(w00, w10); pl16(w01, w11);
        pl32(w20, w30); pl32(w21, w31);
        pl16(w20, w30); pl16(w21, w31);
        union { uint4 u; s16x8 v; } Pb0, Pb1;
        Pb0.u = make_uint4(w00, w01, w10, w11);
        Pb1.u = make_uint4(w20, w21, w30, w31);
        const s16x8 pb0 = Pb0.v, pb1 = Pb1.v;

        // ---- PV + l via ones-MFMA accumulator ----
        acc0 = __builtin_amdgcn_mfma_f32_16x16x32_bf16(va0, pb0, acc0, 0, 0, 0);
        acc0 = __builtin_amdgcn_mfma_f32_16x16x32_bf16(va1, pb1, acc0, 0, 0, 0);
        acc1 = __builtin_amdgcn_mfma_f32_16x16x32_bf16(va2, pb0, acc1, 0, 0, 0);
        acc1 = __builtin_amdgcn_mfma_f32_16x16x32_bf16(va3, pb1, acc1, 0, 0, 0);
        lacc = __builtin_amdgcn_mfma_f32_16x16x32_bf16(ones, pb0, lacc, 0, 0, 0);
        lacc = __builtin_amdgcn_mfma_f32_16x16x32_bf16(ones, pb1, lacc, 0, 0, 0);
    }

    // ---- write fp32 partials ----
    const float l = lacc[0];
    float* pa = pacc + (((size_t)bh * STRIPS + strip) * NL + (qw + lc)) * 32;
    *(f32x4*)(pa + 4 * g) = acc0;
    *(f32x4*)(pa + 16 + 4 * g) = acc1;
    if (g == 0) {
        *(float2*)(pml + (((size_t)bh * STRIPS + strip) * NL + (qw + lc)) * 2) =
            make_float2(m, l);
    }
}

// ==== combine kernel (2 strips) ====
__global__ __launch_bounds__(256) void ga_combine(const float* __restrict__ pacc,
                                                  const float* __restrict__ pml,
                                                  float* __restrict__ O) {
    const int tid = blockIdx.x * 256 + threadIdx.x;
    const int dq = tid & 7, q = (tid >> 3) & 2047, bh = tid >> 14;
    const int b = bh >> 3, h = bh & 7;
    float2 t0 = *(const float2*)(pml + (((size_t)bh * STRIPS + 0) * NL + q) * 2);
    float2 t1 = *(const float2*)(pml + (((size_t)bh * STRIPS + 1) * NL + q) * 2);
    const float mf = fmaxf(t0.x, t1.x);
    float w0 = __builtin_amdgcn_exp2f((t0.x - mf) * CSC);
    float w1 = __builtin_amdgcn_exp2f((t1.x - mf) * CSC);
    const float inv = 1.f / fmaf(t0.y, w0, t1.y * w1);
    w0 *= inv;
    w1 *= inv;
    const float* pa0 = pacc + (((size_t)bh * STRIPS + 0) * NL + q) * 32 + dq * 4;
    const float* pa1 = pacc + (((size_t)bh * STRIPS + 1) * NL + q) * 32 + dq * 4;
    float4 a0 = *(const float4*)pa0, a1 = *(const float4*)pa1;
    float4 o;
    o.x = fmaf(a0.x, w0, a1.x * w1);
    o.y = fmaf(a0.y, w0, a1.y * w1);
    o.z = fmaf(a0.z, w0, a1.z * w1);
    o.w = fmaf(a0.w, w0, a1.w * w1);
    *(float4*)(O + (((size_t)(b * NL + q)) * NH + h) * 32 + dq * 4) = o;
}

// ==== fallback: round-4 kernel (validated), used only if ws too small ====
__global__ __launch_bounds__(512, 4) void ga_fallback(
    const float* __restrict__ Q, const float* __restrict__ K,
    const float* __restrict__ V, float* __restrict__ O) {
    __shared__ union {
        struct {
            u16 Kh[2][64][32];
            u16 Kl[2][64][32];
            u16 Vt[2][32][64];
            float kn2[2][64];
        } s;
        struct { float acc[8][32][17]; float m[8][16]; float l[8][16]; } c;
    } u;
    __shared__ u16 sP[8][16][64];

    const int T = threadIdx.x;
    const int lane = T & 63, wave = T >> 6;
    const int g = lane >> 4, lc = lane & 15, g8 = g * 8;
    const int half = wave >> 2;
    const int qt = blockIdx.x & 31;
    const int bh = blockIdx.x >> 5;
    const int b = bh >> 3, h = bh & 7;
    const int qw = qt * 64 + (wave & 3) * 16;

    const float* qrow = Q + ((size_t)((b * NL + qw + lc) * NH + h)) * 32 + g8;
    float4 qa = *(const float4*)qrow, qb = *(const float4*)(qrow + 4);
    float q8[8] = {qa.x, qa.y, qa.z, qa.w, qb.x, qb.y, qb.z, qb.w};
    union { unsigned u4[4]; s16x8 v; } qh_, ql_;
    float qn2 = 0.f;
#pragma unroll
    for (int i = 0; i < 4; i++) {
        float x0 = q8[2 * i], x1 = q8[2 * i + 1];
        qn2 = fmaf(x0, x0, qn2);
        qn2 = fmaf(x1, x1, qn2);
        unsigned h01 = pk2(x0, x1);
        qh_.u4[i] = h01;
        float h0 = __uint_as_float(h01 << 16);
        float h1 = __uint_as_float(h01 & 0xffff0000u);
        ql_.u4[i] = pk2(x0 - h0, x1 - h1);
    }
    const s16x8 qh = qh_.v, ql = ql_.v;
    qn2 += __shfl_xor(qn2, 16);
    qn2 += __shfl_xor(qn2, 32);

    const int Tl = T & 255;
    const int sk = Tl >> 2, kc = Tl & 3;
    const int dv = Tl & 31, vc = Tl >> 5;
    const float* kbase = K + ((size_t)(b * NS * NH) + h) * 32;
    const float* vbase = V + ((size_t)(b * NS * NH) + h) * 32;
    const int kphys = (kc ^ swzK(sk)) * 8;
    const int vphys = (vc ^ swzV(dv)) * 8;

    int s0 = half * 1024;
    float4 ka = *(const float4*)(kbase + (size_t)(s0 + sk) * 256 + kc * 8);
    float4 kb = *(const float4*)(kbase + (size_t)(s0 + sk) * 256 + kc * 8 + 4);
    float vr[8];
#pragma unroll
    for (int i = 0; i < 8; i++) vr[i] = vbase[(size_t)(s0 + 8 * vc + i) * 256 + dv];

    f32x4 acc0 = {0.f, 0.f, 0.f, 0.f}, acc1 = {0.f, 0.f, 0.f, 0.f};
    float m = -INFINITY, l = 0.f;

    for (int t = 0; t < 16; ++t) {
        {
            float kx[8] = {ka.x, ka.y, ka.z, ka.w, kb.x, kb.y, kb.z, kb.w};
            unsigned hh[4], ll[4];
            float kn2p = 0.f;
#pragma unroll
            for (int i = 0; i < 4; i++) {
                float x0 = kx[2 * i], x1 = kx[2 * i + 1];
                kn2p = fmaf(x0, x0, kn2p);
                kn2p = fmaf(x1, x1, kn2p);
                unsigned h01 = pk2(x0, x1);
                hh[i] = h01;
                float h0 = __uint_as_float(h01 << 16);
                float h1 = __uint_as_float(h01 & 0xffff0000u);
                ll[i] = pk2(x0 - h0, x1 - h1);
            }
            *(uint4*)&u.s.Kh[half][sk][kphys] = make_uint4(hh[0], hh[1], hh[2], hh[3]);
            *(uint4*)&u.s.Kl[half][sk][kphys] = make_uint4(ll[0], ll[1], ll[2], ll[3]);
            kn2p = dpp_add<0xB1>(kn2p);
            kn2p = dpp_add<0x4E>(kn2p);
            if (kc == 0) u.s.kn2[half][sk] = kn2p;
            *(uint4*)&u.s.Vt[half][dv][vphys] =
                make_uint4(pk2(vr[0], vr[1]), pk2(vr[2], vr[3]),
                           pk2(vr[4], vr[5]), pk2(vr[6], vr[7]));
        }
        const int tn = (t + 1 < 16) ? t + 1 : t;
        const int sn = half * 1024 + tn * 64;
        ka = *(const float4*)(kbase + (size_t)(sn + sk) * 256 + kc * 8);
        kb = *(const float4*)(kbase + (size_t)(sn + sk) * 256 + kc * 8 + 4);
#pragma unroll
        for (int i = 0; i < 8; i++) vr[i] = vbase[(size_t)(sn + 8 * vc + i) * 256 + dv];

        __syncthreads();

        f32x4 d[4], kn2v[4];
        const f32x4 z = {0.f, 0.f, 0.f, 0.f};
        const int skr = swzK(lc);
#pragma unroll
        for (int st = 0; st < 4; st++) {
            kn2v[st] = *(f32x4*)&u.s.kn2[half][16 * st + 4 * g];
            s16x8 kh = *(s16x8*)&u.s.Kh[half][16 * st + lc][(g ^ skr) * 8];
            s16x8 kl = *(s16x8*)&u.s.Kl[half][16 * st + lc][(g ^ skr) * 8];
            f32x4 dd = __builtin_amdgcn_mfma_f32_16x16x32_bf16(kl, qh, z, 0, 0, 0);
            dd = __builtin_amdgcn_mfma_f32_16x16x32_bf16(kh, ql, dd, 0, 0, 0);
            dd = __builtin_amdgcn_mfma_f32_16x16x32_bf16(kh, qh, dd, 0, 0, 0);
            d[st] = dd;
        }

        float sc[4][4];
#pragma unroll
        for (int st = 0; st < 4; st++)
#pragma unroll
            for (int r = 0; r < 4; r++) {
                float dd = d[st][r];
                float w = fmaxf(fmaf(-dd, dd, qn2 * kn2v[st][r]), 0.f);
                sc[st][r] = (dd - w) * CSC;
            }

        float x0 = fmaxf(fmaxf(sc[0][0], sc[0][1]), fmaxf(sc[0][2], sc[0][3]));
        float x1 = fmaxf(fmaxf(sc[1][0], sc[1][1]), fmaxf(sc[1][2], sc[1][3]));
        float x2 = fmaxf(fmaxf(sc[2][0], sc[2][1]), fmaxf(sc[2][2], sc[2][3]));
        float x3 = fmaxf(fmaxf(sc[3][0], sc[3][1]), fmaxf(sc[3][2], sc[3][3]));
        float tm = fmaxf(fmaxf(x0, x1), fmaxf(x2, x3));
        tm = fmaxf(tm, __shfl_xor(tm, 16));
        tm = fmaxf(tm, __shfl_xor(tm, 32));
        const float nm = fmaxf(m, tm);
        const float al = __builtin_amdgcn_exp2f(m - nm);
        m = nm;
        float p[4][4], ls = 0.f;
#pragma unroll
        for (int st = 0; st < 4; st++)
#pragma unroll
            for (int r = 0; r < 4; r++) {
                p[st][r] = __builtin_amdgcn_exp2f(sc[st][r] - nm);
                ls += p[st][r];
            }
        l = fmaf(l, al, ls);
        acc0 *= al;
        acc1 *= al;

#pragma unroll
        for (int st = 0; st < 4; st++) {
            const int off = ((2 * st + (g >> 1)) ^ (lc & 7)) * 8 + (g & 1) * 4;
            *(uint2*)&sP[wave][lc][off] =
                make_uint2(pk2(p[st][0], p[st][1]), pk2(p[st][2], p[st][3]));
        }
        __builtin_amdgcn_s_waitcnt(0xC07F);

        const int svl = swzV(lc), svh = swzV(lc + 16), spl = lc & 7;
        s16x8 va00 = *(s16x8*)&u.s.Vt[half][lc][(g ^ svl) * 8];
        s16x8 va01 = *(s16x8*)&u.s.Vt[half][lc][((4 + g) ^ svl) * 8];
        s16x8 va10 = *(s16x8*)&u.s.Vt[half][lc + 16][(g ^ svh) * 8];
        s16x8 va11 = *(s16x8*)&u.s.Vt[half][lc + 16][((4 + g) ^ svh) * 8];
        s16x8 pb0 = *(s16x8*)&sP[wave][lc][(g ^ spl) * 8];
        s16x8 pb1 = *(s16x8*)&sP[wave][lc][((4 + g) ^ spl) * 8];
        acc0 = __builtin_amdgcn_mfma_f32_16x16x32_bf16(va00, pb0, acc0, 0, 0, 0);
        acc0 = __builtin_amdgcn_mfma_f32_16x16x32_bf16(va01, pb1, acc0, 0, 0, 0);
        acc1 = __builtin_amdgcn_mfma_f32_16x16x32_bf16(va10, pb0, acc1, 0, 0, 0);
        acc1 = __builtin_amdgcn_mfma_f32_16x16x32_bf16(va11, pb1, acc1, 0, 0, 0);

        __syncthreads();
    }

    l += __shfl_xor(l, 16);
    l += __shfl_xor(l, 32);
#pragma unroll
    for (int r = 0; r < 4; r++) {
        u.c.acc[wave][4 * g + r][lc] = acc0[r];
        u.c.acc[wave][16 + 4 * g + r][lc] = acc1[r];
    }
    if (lane < 16) {
        u.c.m[wave][lc] = m;
        u.c.l[wave][lc] = l;
    }
    __syncthreads();

    const int q = T >> 3, dq = (T & 7) * 4, qr = q & 15;
    const int w0 = q >> 4, w1 = w0 + 4;
    float m0 = u.c.m[w0][qr], m1 = u.c.m[w1][qr];
    float l0 = u.c.l[w0][qr], l1 = u.c.l[w1][qr];
    float mf = fmaxf(m0, m1);
    float e0 = __builtin_amdgcn_exp2f(m0 - mf);
    float e1 = __builtin_amdgcn_exp2f(m1 - mf);
    float inv = 1.f / fmaf(l1, e1, l0 * e0);
    e0 *= inv;
    e1 *= inv;
    float4 o;
    o.x = u.c.acc[w0][dq + 0][qr] * e0 + u.c.acc[w1][dq + 0][qr] * e1;
    o.y = u.c.acc[w0][dq + 1][qr] * e0 + u.c.acc[w1][dq + 1][qr] * e1;
    o.z = u.c.acc[w0][dq + 2][qr] * e0 + u.c.acc[w1][dq + 2][qr] * e1;
    o.w = u.c.acc[w0][dq + 3][qr] * e0 + u.c.acc[w1][dq + 3][qr] * e1;
    *(float4*)(O + ((size_t)((b * NL + qt * 64 + q) * NH + h)) * 32 + dq) = o;
}

extern "C" void kernel_launch(void* const* d_in, const int* in_sizes, int n_in,
                              void* d_out, int out_size, void* d_ws, size_t ws_size,
                              hipStream_t stream) {
    const float* Q = (const float*)d_in[0];
    const float* K = (const float*)d_in[1];
    const float* V = (const float*)d_in[2];
    float* O = (float*)d_out;

    if (ws_size >= (size_t)WS_NEED) {
        float* kn2w = (float*)((char*)d_ws + WS_KN2_OFF);
        u16* khkl = (u16*)((char*)d_ws + WS_KHKL_OFF);
        u16* vtw = (u16*)((char*)d_ws + WS_VT_OFF);
        float* pacc = (float*)((char*)d_ws + WS_PACC_OFF);
        float* pml = (float*)((char*)d_ws + WS_PML_OFF);
        ga_pre<<<NBH * 32, 256, 0, stream>>>(K, V, kn2w, khkl, vtw);
        ga_reg<<<NBH * 32 * STRIPS, 256, 0, stream>>>(Q, kn2w, khkl, vtw, pacc, pml);
        ga_combine<<<(NBH * NL * 8) / 256, 256, 0, stream>>>(pacc, pml, O);
    } else {
        ga_fallback<<<NBH * 32, 512, 0, stream>>>(Q, K, V, O);
    }
}

// Round 4
// 105.004 us; speedup vs baseline: 1.5548x; 1.5548x over previous
//
#include <hip/hip_runtime.h>
#include <hip/hip_bf16.h>
#include <math.h>

// GeomAttention: B=2, L=S=2048, H=8, E=D=32, fp32 in/out.
// scores = (0.5*dot - 0.5*relu(qn2*kn2 - dot^2))/sqrt(E); softmax over S; out = attn@V.
// Round 11: 32 queries/wave (two q-subtiles). R3 post-mortem: per-wave global
// fragments get register-serialized (VGPR=48) -> 101us. R1's LDS version is
// co-limited by LDS port (4x read amplification) + barrier idle. Reusing each
// K/V LDS fragment for TWO q-subtiles halves LDS bytes/(q,k) and doubles
// per-wave work between barriers -> pipes fill. STRIPS=4, NT=8, grid 1024.

#define NB 2
#define NL 2048
#define NS 2048
#define NH 8
#define NBH 16
#define STRIPS 4
#define NT 8                  // 64-key tiles per strip
#define CSC 0.12751742f       // 0.5 / sqrt(32) * log2(e)
#define DEFER_THR 24.0f       // p <= 2^(24*CSC) ~= 8.4, safe in bf16

#define WS_KN2_OFF 0u
#define WS_KHKL_OFF 131072u                          // 16*2048 f32
#define WS_VT_OFF (131072u + 4194304u)               // + 16*2048*128B (K hi/lo image)
#define WS_PACC_OFF (131072u + 4194304u + 2097152u)  // + 16*32*2048*2B (V^T image)
#define WS_PML_OFF (WS_PACC_OFF + 16777216u)         // + 16*4*2048*32 f32
#define WS_NEED (WS_PML_OFF + 1048576u)              // + 16*4*2048*2 f32 = 24,248,320 B

typedef float f32x4 __attribute__((ext_vector_type(4)));
typedef float f32x2 __attribute__((ext_vector_type(2)));
typedef short s16x8 __attribute__((ext_vector_type(8)));
typedef unsigned short u16;

__device__ inline unsigned pk2(float a, float b) {  // bf16(a)|bf16(b)<<16, RNE
    __hip_bfloat162 t = __float22bfloat162_rn(make_float2(a, b));
    union { __hip_bfloat162 h; unsigned u; } cv;
    cv.h = t;
    return cv.u;
}
template <int CTRL>
__device__ inline float dpp_add(float x) {
    return x + __int_as_float(__builtin_amdgcn_mov_dpp(__float_as_int(x), CTRL, 0xF, 0xF, false));
}
// async global->LDS DMA, 16 B/lane; LDS dest = uniform base + lane*16 [m97/m104]
__device__ inline void dma16(const void* gp, void* lp) {
    __builtin_amdgcn_global_load_lds(
        (__attribute__((address_space(1))) void*)(void*)gp,
        (__attribute__((address_space(3))) void*)lp, 16, 0, 0);
}
// gfx950 cross-lane row swaps (both operands read-write)
__device__ inline void pl32(unsigned& a, unsigned& b) {
    asm("v_permlane32_swap_b32 %0, %1" : "+v"(a), "+v"(b));
}
__device__ inline void pl16(unsigned& a, unsigned& b) {
    asm("v_permlane16_swap_b32 %0, %1" : "+v"(a), "+v"(b));
}
// fallback-kernel swizzles
__device__ inline int swzK(int row) { return (row ^ (row >> 2)) & 3; }
__device__ inline int swzV(int row) { return (row + (row >> 3)) & 7; }

// ==== pre-kernel: swizzled LDS-image layouts ====
// K image: [bh][key][8 chunks x 16B], phys = logical ^ (key&7); logical 0-3 = hi, 4-7 = lo.
// V image: [bh][d][s], per-64-key tile 8 chunks, phys = logical ^ (d&7). kn2 exact fp32.
__global__ __launch_bounds__(256) void ga_pre(const float* __restrict__ K,
                                              const float* __restrict__ V,
                                              float* __restrict__ kn2w,
                                              u16* __restrict__ khkl,
                                              u16* __restrict__ vtw) {
    __shared__ float Vf[64][36];
    const int T = threadIdx.x;
    const int bh = blockIdx.x >> 5, stile = blockIdx.x & 31;
    const int b = bh >> 3, h = bh & 7;
    const int s0 = stile * 64;
    const int sk = T >> 2, kc = T & 3;

    const float* kp = K + ((size_t)((b * NS + s0 + sk) * NH + h)) * 32 + kc * 8;
    float4 f0 = *(const float4*)kp, f1 = *(const float4*)(kp + 4);
    float kx[8] = {f0.x, f0.y, f0.z, f0.w, f1.x, f1.y, f1.z, f1.w};
    unsigned hh[4], ll[4];
    float kn2p = 0.f;
#pragma unroll
    for (int i = 0; i < 4; i++) {
        float x0 = kx[2 * i], x1 = kx[2 * i + 1];
        kn2p = fmaf(x0, x0, kn2p);
        kn2p = fmaf(x1, x1, kn2p);
        unsigned h01 = pk2(x0, x1);
        hh[i] = h01;
        float h0 = __uint_as_float(h01 << 16);
        float h1 = __uint_as_float(h01 & 0xffff0000u);
        ll[i] = pk2(x0 - h0, x1 - h1);
    }
    u16* kd = khkl + ((size_t)(bh * NS + s0 + sk)) * 64;
    const int swk = sk & 7;
    *(uint4*)(kd + ((kc ^ swk) * 8)) = make_uint4(hh[0], hh[1], hh[2], hh[3]);
    *(uint4*)(kd + (((4 + kc) ^ swk) * 8)) = make_uint4(ll[0], ll[1], ll[2], ll[3]);
    kn2p = dpp_add<0xB1>(kn2p);
    kn2p = dpp_add<0x4E>(kn2p);
    if (kc == 0) kn2w[bh * NS + s0 + sk] = kn2p;

    const float* vp = V + ((size_t)((b * NS + s0 + sk) * NH + h)) * 32 + kc * 8;
    float4 g0 = *(const float4*)vp, g1 = *(const float4*)(vp + 4);
    // chunk swizzle keyed on (row>>3)&3 so the column-wise read below is <=2-way banked
    const int chv = kc ^ ((sk >> 3) & 3);
    *(float4*)&Vf[sk][chv * 8] = g0;
    *(float4*)&Vf[sk][chv * 8 + 4] = g1;
    __syncthreads();
    const int dr = T >> 3, c = T & 7;
    float vv[8];
#pragma unroll
    for (int i = 0; i < 8; i++)
        vv[i] = Vf[c * 8 + i][(((dr >> 3) ^ (c & 3)) << 3) + (dr & 7)];
    const int phys = c ^ (dr & 7);
    *(uint4*)(vtw + ((size_t)(bh * 32 + dr)) * NS + s0 + phys * 8) =
        make_uint4(pk2(vv[0], vv[1]), pk2(vv[2], vv[3]), pk2(vv[4], vv[5]), pk2(vv[6], vv[7]));
}

// ==== main kernel: DMA-staged, double-buffered, 32 queries/wave ====
__global__ __launch_bounds__(256, 3) void ga_dma(
    const float* __restrict__ Q, const float* __restrict__ kn2w,
    const u16* __restrict__ khkl, const u16* __restrict__ vtw,
    float* __restrict__ pacc, float* __restrict__ pml) {
    __shared__ u16 sK[2][64][64];  // [buf][key][8 phys chunks x 8 u16]  16 KB
    __shared__ u16 sV[2][32][64];  // [buf][d][8 phys chunks]             8 KB

    const int T = threadIdx.x;
    const int lane = T & 63, wave = T >> 6;
    const int g = lane >> 4, lc = lane & 15, g8 = g * 8;
    const int blk = blockIdx.x;
    const int qt = blk & 15, strip = (blk >> 4) & 3, bh = blk >> 6;
    const int b = bh >> 3, h = bh & 7;
    const int qwa = qt * 128 + wave * 16;  // q-subtile a
    const int qwb = qwa + 64;              // q-subtile b
    const int kb0 = strip * 512;

    // ---- Q fragments (hi/lo bf16) + exact qn2, for BOTH sub-tiles ----
    s16x8 qha, qla, qhb, qlb;
    float qn2a, qn2b;
    {
        const float* qrow = Q + ((size_t)((b * NL + qwa + lc) * NH + h)) * 32 + g8;
        float4 qa = *(const float4*)qrow, qb = *(const float4*)(qrow + 4);
        float q8[8] = {qa.x, qa.y, qa.z, qa.w, qb.x, qb.y, qb.z, qb.w};
        union { unsigned u4[4]; s16x8 v; } qh_, ql_;
        float qn2 = 0.f;
#pragma unroll
        for (int i = 0; i < 4; i++) {
            float x0 = q8[2 * i], x1 = q8[2 * i + 1];
            qn2 = fmaf(x0, x0, qn2);
            qn2 = fmaf(x1, x1, qn2);
            unsigned h01 = pk2(x0, x1);
            qh_.u4[i] = h01;
            float h0 = __uint_as_float(h01 << 16);
            float h1 = __uint_as_float(h01 & 0xffff0000u);
            ql_.u4[i] = pk2(x0 - h0, x1 - h1);
        }
        qha = qh_.v; qla = ql_.v;
        qn2 += __shfl_xor(qn2, 16);
        qn2 += __shfl_xor(qn2, 32);
        qn2a = qn2;
    }
    {
        const float* qrow = Q + ((size_t)((b * NL + qwb + lc) * NH + h)) * 32 + g8;
        float4 qa = *(const float4*)qrow, qb = *(const float4*)(qrow + 4);
        float q8[8] = {qa.x, qa.y, qa.z, qa.w, qb.x, qb.y, qb.z, qb.w};
        union { unsigned u4[4]; s16x8 v; } qh_, ql_;
        float qn2 = 0.f;
#pragma unroll
        for (int i = 0; i < 4; i++) {
            float x0 = q8[2 * i], x1 = q8[2 * i + 1];
            qn2 = fmaf(x0, x0, qn2);
            qn2 = fmaf(x1, x1, qn2);
            unsigned h01 = pk2(x0, x1);
            qh_.u4[i] = h01;
            float h0 = __uint_as_float(h01 << 16);
            float h1 = __uint_as_float(h01 & 0xffff0000u);
            ql_.u4[i] = pk2(x0 - h0, x1 - h1);
        }
        qhb = qh_.v; qlb = ql_.v;
        qn2 += __shfl_xor(qn2, 16);
        qn2 += __shfl_xor(qn2, 32);
        qn2b = qn2;
    }

    // ---- DMA source pointers (coalesced; ws layout == LDS image) ----
    const char* ksrc = (const char*)khkl +
        ((size_t)(bh * NS + kb0 + 16 * wave)) * 128 + lane * 16;
    const char* vsrc = (const char*)vtw +
        ((size_t)(bh * 32 + 8 * wave + (lane >> 3))) * (NS * 2) +
        (size_t)(kb0 + (lane & 7) * 8) * 2;
    const float* kn2b = kn2w + (size_t)bh * NS + kb0 + 4 * g;

    // ---- prologue: stage tile 0 into buf 0 ----
    dma16(ksrc, &sK[0][16 * wave][0]);
    dma16(ksrc + 1024, &sK[0][16 * wave + 8][0]);
    dma16(vsrc, &sV[0][8 * wave][0]);
    __syncthreads();  // drains vmcnt -> tile 0 in LDS

    s16x8 ones;
#pragma unroll
    for (int i = 0; i < 8; i++) ones[i] = (short)0x3F80;  // bf16 1.0

    f32x4 acc0a = {0.f, 0.f, 0.f, 0.f}, acc1a = {0.f, 0.f, 0.f, 0.f};
    f32x4 acc0b = {0.f, 0.f, 0.f, 0.f}, acc1b = {0.f, 0.f, 0.f, 0.f};
    f32x4 lacca = {0.f, 0.f, 0.f, 0.f}, laccb = {0.f, 0.f, 0.f, 0.f};
    float ma = -1e30f, mb = -1e30f;
    const f32x4 z = {0.f, 0.f, 0.f, 0.f};
    const int sw = lc & 7;

#pragma unroll 1
    for (int t = 0; t < NT; ++t) {
        const int cur = t & 1;
        // ---- issue DMA for tile t+1 (overlaps compute) ----
        if (t + 1 < NT) {
            const char* k2 = ksrc + (size_t)(t + 1) * 8192;
            const char* v2 = vsrc + (size_t)(t + 1) * 128;
            dma16(k2, &sK[cur ^ 1][16 * wave][0]);
            dma16(k2 + 1024, &sK[cur ^ 1][16 * wave + 8][0]);
            dma16(v2, &sV[cur ^ 1][8 * wave][0]);
        }

        // ---- QK^T for both q-subtiles from the SAME K fragments ----
        f32x4 da[4], db[4], kn2m[4];
#pragma unroll
        for (int st = 0; st < 4; st++) {
            kn2m[st] = *(const f32x4*)(kn2b + t * 64 + 16 * st);
            s16x8 kh = *(s16x8*)&sK[cur][16 * st + lc][(g ^ sw) * 8];
            s16x8 klo = *(s16x8*)&sK[cur][16 * st + lc][((4 + g) ^ sw) * 8];
            f32x4 dd = __builtin_amdgcn_mfma_f32_16x16x32_bf16(klo, qha, z, 0, 0, 0);
            dd = __builtin_amdgcn_mfma_f32_16x16x32_bf16(kh, qla, dd, 0, 0, 0);
            da[st] = __builtin_amdgcn_mfma_f32_16x16x32_bf16(kh, qha, dd, 0, 0, 0);
            f32x4 de = __builtin_amdgcn_mfma_f32_16x16x32_bf16(klo, qhb, z, 0, 0, 0);
            de = __builtin_amdgcn_mfma_f32_16x16x32_bf16(kh, qlb, de, 0, 0, 0);
            db[st] = __builtin_amdgcn_mfma_f32_16x16x32_bf16(kh, qhb, de, 0, 0, 0);
        }
        s16x8 va0 = *(s16x8*)&sV[cur][lc][(g ^ sw) * 8];
        s16x8 va1 = *(s16x8*)&sV[cur][lc][((4 + g) ^ sw) * 8];
        s16x8 va2 = *(s16x8*)&sV[cur][lc + 16][(g ^ sw) * 8];
        s16x8 va3 = *(s16x8*)&sV[cur][lc + 16][((4 + g) ^ sw) * 8];

        // ---- scores: sc = min(d, d + (d^2 - qn2*kn2)) (pre-CSC log2 domain) ----
        float sca[4][4], scb[4][4];
        {
            const f32x2 qa2 = {qn2a, qn2a}, qb2 = {qn2b, qn2b};
#pragma unroll
            for (int st = 0; st < 4; st++) {
                f32x2 kk0 = {kn2m[st][0], kn2m[st][1]}, kk1 = {kn2m[st][2], kn2m[st][3]};
                f32x2 dd0 = {da[st][0], da[st][1]}, dd1 = {da[st][2], da[st][3]};
                f32x2 e0 = dd0 - qa2 * kk0;
                f32x2 e1 = dd1 - qa2 * kk1;
                f32x2 t0 = dd0 * dd0 + e0;
                f32x2 t1 = dd1 * dd1 + e1;
                sca[st][0] = fminf(da[st][0], t0[0]);
                sca[st][1] = fminf(da[st][1], t0[1]);
                sca[st][2] = fminf(da[st][2], t1[0]);
                sca[st][3] = fminf(da[st][3], t1[1]);
                f32x2 ee0 = {db[st][0], db[st][1]}, ee1 = {db[st][2], db[st][3]};
                f32x2 f0 = ee0 - qb2 * kk0;
                f32x2 f1 = ee1 - qb2 * kk1;
                f32x2 u0 = ee0 * ee0 + f0;
                f32x2 u1 = ee1 * ee1 + f1;
                scb[st][0] = fminf(db[st][0], u0[0]);
                scb[st][1] = fminf(db[st][1], u0[1]);
                scb[st][2] = fminf(db[st][2], u1[0]);
                scb[st][3] = fminf(db[st][3], u1[1]);
            }
        }

        // ---- online softmax with deferred max (merged branch) ----
        float a0 = fmaxf(fmaxf(sca[0][0], sca[0][1]), fmaxf(sca[0][2], sca[0][3]));
        float a1 = fmaxf(fmaxf(sca[1][0], sca[1][1]), fmaxf(sca[1][2], sca[1][3]));
        float a2 = fmaxf(fmaxf(sca[2][0], sca[2][1]), fmaxf(sca[2][2], sca[2][3]));
        float a3 = fmaxf(fmaxf(sca[3][0], sca[3][1]), fmaxf(sca[3][2], sca[3][3]));
        float tma = fmaxf(fmaxf(a0, a1), fmaxf(a2, a3));
        float b0 = fmaxf(fmaxf(scb[0][0], scb[0][1]), fmaxf(scb[0][2], scb[0][3]));
        float b1 = fmaxf(fmaxf(scb[1][0], scb[1][1]), fmaxf(scb[1][2], scb[1][3]));
        float b2 = fmaxf(fmaxf(scb[2][0], scb[2][1]), fmaxf(scb[2][2], scb[2][3]));
        float b3 = fmaxf(fmaxf(scb[3][0], scb[3][1]), fmaxf(scb[3][2], scb[3][3]));
        float tmb = fmaxf(fmaxf(b0, b1), fmaxf(b2, b3));
        if (!__all((tma <= ma + DEFER_THR) && (tmb <= mb + DEFER_THR))) {
            tma = fmaxf(tma, __shfl_xor(tma, 16));
            tma = fmaxf(tma, __shfl_xor(tma, 32));
            tmb = fmaxf(tmb, __shfl_xor(tmb, 16));
            tmb = fmaxf(tmb, __shfl_xor(tmb, 32));
            const float nma = fmaxf(ma, tma), nmb = fmaxf(mb, tmb);
            const float ala = __builtin_amdgcn_exp2f((ma - nma) * CSC);
            const float alb = __builtin_amdgcn_exp2f((mb - nmb) * CSC);
            ma = nma; mb = nmb;
            acc0a *= ala; acc1a *= ala; lacca *= ala;
            acc0b *= alb; acc1b *= alb; laccb *= alb;
        }
        const float negmaC = -ma * CSC, negmbC = -mb * CSC;
        const f32x2 cscv = {CSC, CSC};
        const f32x2 nmav = {negmaC, negmaC}, nmbv = {negmbC, negmbC};
        float pa[4][4], pb[4][4];
#pragma unroll
        for (int st = 0; st < 4; st++) {
            f32x2 s0 = {sca[st][0], sca[st][1]}, s1 = {sca[st][2], sca[st][3]};
            f32x2 e0 = s0 * cscv + nmav;
            f32x2 e1 = s1 * cscv + nmav;
            pa[st][0] = __builtin_amdgcn_exp2f(e0[0]);
            pa[st][1] = __builtin_amdgcn_exp2f(e0[1]);
            pa[st][2] = __builtin_amdgcn_exp2f(e1[0]);
            pa[st][3] = __builtin_amdgcn_exp2f(e1[1]);
            f32x2 u0 = {scb[st][0], scb[st][1]}, u1 = {scb[st][2], scb[st][3]};
            f32x2 f0 = u0 * cscv + nmbv;
            f32x2 f1 = u1 * cscv + nmbv;
            pb[st][0] = __builtin_amdgcn_exp2f(f0[0]);
            pb[st][1] = __builtin_amdgcn_exp2f(f0[1]);
            pb[st][2] = __builtin_amdgcn_exp2f(f1[0]);
            pb[st][3] = __builtin_amdgcn_exp2f(f1[1]);
        }

        // ---- P^T in registers: pk2 pack + permlane32/16 swap (both subtiles) ----
        {
            unsigned w00 = pk2(pa[0][0], pa[0][1]), w01 = pk2(pa[0][2], pa[0][3]);
            unsigned w10 = pk2(pa[1][0], pa[1][1]), w11 = pk2(pa[1][2], pa[1][3]);
            unsigned w20 = pk2(pa[2][0], pa[2][1]), w21 = pk2(pa[2][2], pa[2][3]);
            unsigned w30 = pk2(pa[3][0], pa[3][1]), w31 = pk2(pa[3][2], pa[3][3]);
            pl32(w00, w10); pl32(w01, w11);
            pl16(w00, w10); pl16(w01, w11);
            pl32(w20, w30); pl32(w21, w31);
            pl16(w20, w30); pl16(w21, w31);
            union { uint4 u; s16x8 v; } P0, P1;
            P0.u = make_uint4(w00, w01, w10, w11);
            P1.u = make_uint4(w20, w21, w30, w31);
            acc0a = __builtin_amdgcn_mfma_f32_16x16x32_bf16(va0, P0.v, acc0a, 0, 0, 0);
            acc0a = __builtin_amdgcn_mfma_f32_16x16x32_bf16(va1, P1.v, acc0a, 0, 0, 0);
            acc1a = __builtin_amdgcn_mfma_f32_16x16x32_bf16(va2, P0.v, acc1a, 0, 0, 0);
            acc1a = __builtin_amdgcn_mfma_f32_16x16x32_bf16(va3, P1.v, acc1a, 0, 0, 0);
            lacca = __builtin_amdgcn_mfma_f32_16x16x32_bf16(ones, P0.v, lacca, 0, 0, 0);
            lacca = __builtin_amdgcn_mfma_f32_16x16x32_bf16(ones, P1.v, lacca, 0, 0, 0);
        }
        {
            unsigned w00 = pk2(pb[0][0], pb[0][1]), w01 = pk2(pb[0][2], pb[0][3]);
            unsigned w10 = pk2(pb[1][0], pb[1][1]), w11 = pk2(pb[1][2], pb[1][3]);
            unsigned w20 = pk2(pb[2][0], pb[2][1]), w21 = pk2(pb[2][2], pb[2][3]);
            unsigned w30 = pk2(pb[3][0], pb[3][1]), w31 = pk2(pb[3][2], pb[3][3]);
            pl32(w00, w10); pl32(w01, w11);
            pl16(w00, w10); pl16(w01, w11);
            pl32(w20, w30); pl32(w21, w31);
            pl16(w20, w30); pl16(w21, w31);
            union { uint4 u; s16x8 v; } P0, P1;
            P0.u = make_uint4(w00, w01, w10, w11);
            P1.u = make_uint4(w20, w21, w30, w31);
            acc0b = __builtin_amdgcn_mfma_f32_16x16x32_bf16(va0, P0.v, acc0b, 0, 0, 0);
            acc0b = __builtin_amdgcn_mfma_f32_16x16x32_bf16(va1, P1.v, acc0b, 0, 0, 0);
            acc1b = __builtin_amdgcn_mfma_f32_16x16x32_bf16(va2, P0.v, acc1b, 0, 0, 0);
            acc1b = __builtin_amdgcn_mfma_f32_16x16x32_bf16(va3, P1.v, acc1b, 0, 0, 0);
            laccb = __builtin_amdgcn_mfma_f32_16x16x32_bf16(ones, P0.v, laccb, 0, 0, 0);
            laccb = __builtin_amdgcn_mfma_f32_16x16x32_bf16(ones, P1.v, laccb, 0, 0, 0);
        }

        // barrier: (a) everyone done reading buf cur, (b) drains DMA t+1 (vmcnt 0)
        __syncthreads();
    }

    // ---- write fp32 partials (both q-subtiles) ----
    float* paa = pacc + (((size_t)bh * STRIPS + strip) * NL + (qwa + lc)) * 32;
    *(f32x4*)(paa + 4 * g) = acc0a;
    *(f32x4*)(paa + 16 + 4 * g) = acc1a;
    float* pab = pacc + (((size_t)bh * STRIPS + strip) * NL + (qwb + lc)) * 32;
    *(f32x4*)(pab + 4 * g) = acc0b;
    *(f32x4*)(pab + 16 + 4 * g) = acc1b;
    if (g == 0) {
        *(float2*)(pml + (((size_t)bh * STRIPS + strip) * NL + (qwa + lc)) * 2) =
            make_float2(ma, lacca[0]);
        *(float2*)(pml + (((size_t)bh * STRIPS + strip) * NL + (qwb + lc)) * 2) =
            make_float2(mb, laccb[0]);
    }
}

// ==== combine kernel (4 strips) ====
__global__ __launch_bounds__(256) void ga_combine(const float* __restrict__ pacc,
                                                  const float* __restrict__ pml,
                                                  float* __restrict__ O) {
    const int tid = blockIdx.x * 256 + threadIdx.x;
    const int dq = tid & 7, q = (tid >> 3) & 2047, bh = tid >> 14;
    const int b = bh >> 3, h = bh & 7;
    float m[4], l[4];
#pragma unroll
    for (int s = 0; s < 4; s++) {
        float2 t = *(const float2*)(pml + (((size_t)bh * STRIPS + s) * NL + q) * 2);
        m[s] = t.x;
        l[s] = t.y;
    }
    float mf = fmaxf(fmaxf(m[0], m[1]), fmaxf(m[2], m[3]));
    float w[4], L = 0.f;
#pragma unroll
    for (int s = 0; s < 4; s++) {
        w[s] = __builtin_amdgcn_exp2f((m[s] - mf) * CSC);
        L = fmaf(l[s], w[s], L);
    }
    const float inv = 1.f / L;
    float4 o = make_float4(0.f, 0.f, 0.f, 0.f);
#pragma unroll
    for (int s = 0; s < 4; s++) {
        const float* pa = pacc + (((size_t)bh * STRIPS + s) * NL + q) * 32 + dq * 4;
        float4 a = *(const float4*)pa;
        o.x = fmaf(a.x, w[s], o.x);
        o.y = fmaf(a.y, w[s], o.y);
        o.z = fmaf(a.z, w[s], o.z);
        o.w = fmaf(a.w, w[s], o.w);
    }
    o.x *= inv; o.y *= inv; o.z *= inv; o.w *= inv;
    *(float4*)(O + (((size_t)(b * NL + q)) * NH + h) * 32 + dq * 4) = o;
}

// ==== fallback: round-4 kernel (validated), used only if ws too small ====
__global__ __launch_bounds__(512, 4) void ga_fallback(
    const float* __restrict__ Q, const float* __restrict__ K,
    const float* __restrict__ V, float* __restrict__ O) {
    __shared__ union {
        struct {
            u16 Kh[2][64][32];
            u16 Kl[2][64][32];
            u16 Vt[2][32][64];
            float kn2[2][64];
        } s;
        struct { float acc[8][32][17]; float m[8][16]; float l[8][16]; } c;
    } u;
    __shared__ u16 sP[8][16][64];

    const int T = threadIdx.x;
    const int lane = T & 63, wave = T >> 6;
    const int g = lane >> 4, lc = lane & 15, g8 = g * 8;
    const int half = wave >> 2;
    const int qt = blockIdx.x & 31;
    const int bh = blockIdx.x >> 5;
    const int b = bh >> 3, h = bh & 7;
    const int qw = qt * 64 + (wave & 3) * 16;

    const float* qrow = Q + ((size_t)((b * NL + qw + lc) * NH + h)) * 32 + g8;
    float4 qa = *(const float4*)qrow, qb = *(const float4*)(qrow + 4);
    float q8[8] = {qa.x, qa.y, qa.z, qa.w, qb.x, qb.y, qb.z, qb.w};
    union { unsigned u4[4]; s16x8 v; } qh_, ql_;
    float qn2 = 0.f;
#pragma unroll
    for (int i = 0; i < 4; i++) {
        float x0 = q8[2 * i], x1 = q8[2 * i + 1];
        qn2 = fmaf(x0, x0, qn2);
        qn2 = fmaf(x1, x1, qn2);
        unsigned h01 = pk2(x0, x1);
        qh_.u4[i] = h01;
        float h0 = __uint_as_float(h01 << 16);
        float h1 = __uint_as_float(h01 & 0xffff0000u);
        ql_.u4[i] = pk2(x0 - h0, x1 - h1);
    }
    const s16x8 qh = qh_.v, ql = ql_.v;
    qn2 += __shfl_xor(qn2, 16);
    qn2 += __shfl_xor(qn2, 32);

    const int Tl = T & 255;
    const int sk = Tl >> 2, kc = Tl & 3;
    const int dv = Tl & 31, vc = Tl >> 5;
    const float* kbase = K + ((size_t)(b * NS * NH) + h) * 32;
    const float* vbase = V + ((size_t)(b * NS * NH) + h) * 32;
    const int kphys = (kc ^ swzK(sk)) * 8;
    const int vphys = (vc ^ swzV(dv)) * 8;

    int s0 = half * 1024;
    float4 ka = *(const float4*)(kbase + (size_t)(s0 + sk) * 256 + kc * 8);
    float4 kb = *(const float4*)(kbase + (size_t)(s0 + sk) * 256 + kc * 8 + 4);
    float vr[8];
#pragma unroll
    for (int i = 0; i < 8; i++) vr[i] = vbase[(size_t)(s0 + 8 * vc + i) * 256 + dv];

    f32x4 acc0 = {0.f, 0.f, 0.f, 0.f}, acc1 = {0.f, 0.f, 0.f, 0.f};
    float m = -INFINITY, l = 0.f;

    for (int t = 0; t < 16; ++t) {
        {
            float kx[8] = {ka.x, ka.y, ka.z, ka.w, kb.x, kb.y, kb.z, kb.w};
            unsigned hh[4], ll[4];
            float kn2p = 0.f;
#pragma unroll
            for (int i = 0; i < 4; i++) {
                float x0 = kx[2 * i], x1 = kx[2 * i + 1];
                kn2p = fmaf(x0, x0, kn2p);
                kn2p = fmaf(x1, x1, kn2p);
                unsigned h01 = pk2(x0, x1);
                hh[i] = h01;
                float h0 = __uint_as_float(h01 << 16);
                float h1 = __uint_as_float(h01 & 0xffff0000u);
                ll[i] = pk2(x0 - h0, x1 - h1);
            }
            *(uint4*)&u.s.Kh[half][sk][kphys] = make_uint4(hh[0], hh[1], hh[2], hh[3]);
            *(uint4*)&u.s.Kl[half][sk][kphys] = make_uint4(ll[0], ll[1], ll[2], ll[3]);
            kn2p = dpp_add<0xB1>(kn2p);
            kn2p = dpp_add<0x4E>(kn2p);
            if (kc == 0) u.s.kn2[half][sk] = kn2p;
            *(uint4*)&u.s.Vt[half][dv][vphys] =
                make_uint4(pk2(vr[0], vr[1]), pk2(vr[2], vr[3]),
                           pk2(vr[4], vr[5]), pk2(vr[6], vr[7]));
        }
        const int tn = (t + 1 < 16) ? t + 1 : t;
        const int sn = half * 1024 + tn * 64;
        ka = *(const float4*)(kbase + (size_t)(sn + sk) * 256 + kc * 8);
        kb = *(const float4*)(kbase + (size_t)(sn + sk) * 256 + kc * 8 + 4);
#pragma unroll
        for (int i = 0; i < 8; i++) vr[i] = vbase[(size_t)(sn + 8 * vc + i) * 256 + dv];

        __syncthreads();

        f32x4 d[4], kn2v[4];
        const f32x4 z = {0.f, 0.f, 0.f, 0.f};
        const int skr = swzK(lc);
#pragma unroll
        for (int st = 0; st < 4; st++) {
            kn2v[st] = *(f32x4*)&u.s.kn2[half][16 * st + 4 * g];
            s16x8 kh = *(s16x8*)&u.s.Kh[half][16 * st + lc][(g ^ skr) * 8];
            s16x8 kl = *(s16x8*)&u.s.Kl[half][16 * st + lc][(g ^ skr) * 8];
            f32x4 dd = __builtin_amdgcn_mfma_f32_16x16x32_bf16(kl, qh, z, 0, 0, 0);
            dd = __builtin_amdgcn_mfma_f32_16x16x32_bf16(kh, ql, dd, 0, 0, 0);
            dd = __builtin_amdgcn_mfma_f32_16x16x32_bf16(kh, qh, dd, 0, 0, 0);
            d[st] = dd;
        }

        float sc[4][4];
#pragma unroll
        for (int st = 0; st < 4; st++)
#pragma unroll
            for (int r = 0; r < 4; r++) {
                float dd = d[st][r];
                float w = fmaxf(fmaf(-dd, dd, qn2 * kn2v[st][r]), 0.f);
                sc[st][r] = (dd - w) * CSC;
            }

        float x0 = fmaxf(fmaxf(sc[0][0], sc[0][1]), fmaxf(sc[0][2], sc[0][3]));
        float x1 = fmaxf(fmaxf(sc[1][0], sc[1][1]), fmaxf(sc[1][2], sc[1][3]));
        float x2 = fmaxf(fmaxf(sc[2][0], sc[2][1]), fmaxf(sc[2][2], sc[2][3]));
        float x3 = fmaxf(fmaxf(sc[3][0], sc[3][1]), fmaxf(sc[3][2], sc[3][3]));
        float tm = fmaxf(fmaxf(x0, x1), fmaxf(x2, x3));
        tm = fmaxf(tm, __shfl_xor(tm, 16));
        tm = fmaxf(tm, __shfl_xor(tm, 32));
        const float nm = fmaxf(m, tm);
        const float al = __builtin_amdgcn_exp2f(m - nm);
        m = nm;
        float p[4][4], ls = 0.f;
#pragma unroll
        for (int st = 0; st < 4; st++)
#pragma unroll
            for (int r = 0; r < 4; r++) {
                p[st][r] = __builtin_amdgcn_exp2f(sc[st][r] - nm);
                ls += p[st][r];
            }
        l = fmaf(l, al, ls);
        acc0 *= al;
        acc1 *= al;

#pragma unroll
        for (int st = 0; st < 4; st++) {
            const int off = ((2 * st + (g >> 1)) ^ (lc & 7)) * 8 + (g & 1) * 4;
            *(uint2*)&sP[wave][lc][off] =
                make_uint2(pk2(p[st][0], p[st][1]), pk2(p[st][2], p[st][3]));
        }
        __builtin_amdgcn_s_waitcnt(0xC07F);

        const int svl = swzV(lc), svh = swzV(lc + 16), spl = lc & 7;
        s16x8 va00 = *(s16x8*)&u.s.Vt[half][lc][(g ^ svl) * 8];
        s16x8 va01 = *(s16x8*)&u.s.Vt[half][lc][((4 + g) ^ svl) * 8];
        s16x8 va10 = *(s16x8*)&u.s.Vt[half][lc + 16][(g ^ svh) * 8];
        s16x8 va11 = *(s16x8*)&u.s.Vt[half][lc + 16][((4 + g) ^ svh) * 8];
        s16x8 pb0 = *(s16x8*)&sP[wave][lc][(g ^ spl) * 8];
        s16x8 pb1 = *(s16x8*)&sP[wave][lc][((4 + g) ^ spl) * 8];
        acc0 = __builtin_amdgcn_mfma_f32_16x16x32_bf16(va00, pb0, acc0, 0, 0, 0);
        acc0 = __builtin_amdgcn_mfma_f32_16x16x32_bf16(va01, pb1, acc0, 0, 0, 0);
        acc1 = __builtin_amdgcn_mfma_f32_16x16x32_bf16(va10, pb0, acc1, 0, 0, 0);
        acc1 = __builtin_amdgcn_mfma_f32_16x16x32_bf16(va11, pb1, acc1, 0, 0, 0);

        __syncthreads();
    }

    l += __shfl_xor(l, 16);
    l += __shfl_xor(l, 32);
#pragma unroll
    for (int r = 0; r < 4; r++) {
        u.c.acc[wave][4 * g + r][lc] = acc0[r];
        u.c.acc[wave][16 + 4 * g + r][lc] = acc1[r];
    }
    if (lane < 16) {
        u.c.m[wave][lc] = m;
        u.c.l[wave][lc] = l;
    }
    __syncthreads();

    const int q = T >> 3, dq = (T & 7) * 4, qr = q & 15;
    const int w0 = q >> 4, w1 = w0 + 4;
    float m0 = u.c.m[w0][qr], m1 = u.c.m[w1][qr];
    float l0 = u.c.l[w0][qr], l1 = u.c.l[w1][qr];
    float mf = fmaxf(m0, m1);
    float e0 = __builtin_amdgcn_exp2f(m0 - mf);
    float e1 = __builtin_amdgcn_exp2f(m1 - mf);
    float inv = 1.f / fmaf(l1, e1, l0 * e0);
    e0 *= inv;
    e1 *= inv;
    float4 o;
    o.x = u.c.acc[w0][dq + 0][qr] * e0 + u.c.acc[w1][dq + 0][qr] * e1;
    o.y = u.c.acc[w0][dq + 1][qr] * e0 + u.c.acc[w1][dq + 1][qr] * e1;
    o.z = u.c.acc[w0][dq + 2][qr] * e0 + u.c.acc[w1][dq + 2][qr] * e1;
    o.w = u.c.acc[w0][dq + 3][qr] * e0 + u.c.acc[w1][dq + 3][qr] * e1;
    *(float4*)(O + ((size_t)((b * NL + qt * 64 + q) * NH + h)) * 32 + dq) = o;
}

extern "C" void kernel_launch(void* const* d_in, const int* in_sizes, int n_in,
                              void* d_out, int out_size, void* d_ws, size_t ws_size,
                              hipStream_t stream) {
    const float* Q = (const float*)d_in[0];
    const float* K = (const float*)d_in[1];
    const float* V = (const float*)d_in[2];
    float* O = (float*)d_out;

    if (ws_size >= (size_t)WS_NEED) {
        float* kn2w = (float*)((char*)d_ws + WS_KN2_OFF);
        u16* khkl = (u16*)((char*)d_ws + WS_KHKL_OFF);
        u16* vtw = (u16*)((char*)d_ws + WS_VT_OFF);
        float* pacc = (float*)((char*)d_ws + WS_PACC_OFF);
        float* pml = (float*)((char*)d_ws + WS_PML_OFF);
        ga_pre<<<NBH * 32, 256, 0, stream>>>(K, V, kn2w, khkl, vtw);
        ga_dma<<<NBH * 16 * STRIPS, 256, 0, stream>>>(Q, kn2w, khkl, vtw, pacc, pml);
        ga_combine<<<(NBH * NL * 8) / 256, 256, 0, stream>>>(pacc, pml, O);
    } else {
        ga_fallback<<<NBH * 32, 512, 0, stream>>>(Q, K, V, O);
    }
}